// Round 8
// baseline (11.350 us; speedup 1.0000x reference)
//
#include <hip/hip_runtime.h>
#include <math.h>

#define N_STATE 32

typedef _Float16 f16;
typedef __fp16 fp16x2 __attribute__((ext_vector_type(2)));
typedef f16 f16x8 __attribute__((ext_vector_type(8)));
typedef float f32x4 __attribute__((ext_vector_type(4)));

// Swizzled byte offset inside a [64 rows][64 f16] table (128 B rows).
// XOR of (row&7) into byte bits 4-6 spreads column-slice ds_read_b128s
// (fixed k, varying row) across banks; same function on write & read
// (rule #21). XOR touches bits 4-6 only -> 4B/8B/16B units stay intact.
__device__ __forceinline__ unsigned swz(int row, int byte_in_row) {
  return (unsigned)(((row << 7) + byte_in_row) ^ ((row & 7) << 4));
}

// Output-staging swizzle on fp32 word index (logical word 64*a + b).
__device__ __forceinline__ unsigned oswz(unsigned word) {
  return word ^ (((word >> 6) & 7u) << 2);
}

// softplus via HW transcendentals: ln(1+e^x) = ln2 * log2(1 + exp2(x*log2e)).
__device__ __forceinline__ float softplus_hw(float x) {
  const float t = __builtin_amdgcn_exp2f(x * 1.4426950408889634f);
  return 0.6931471805599453f * __builtin_amdgcn_logf(1.0f + t);
}

// One block (256 threads = 4 waves) per row d.
//   K[d, 64a+b] = sum_k V'[b,k] U'[k,a]   (V as MFMA-A, U as MFMA-B)
//   V'[b,2n] = Re(z_n^b),  V'[b,2n+1] = -Im(z_n^b)
//   U'[2n,a] = Re(G M^a),  U'[2n+1,a] =  Im(G M^a)
// z = exp(dt*A), M = z^64, G = Cc*Bc. f16 operands, fp32 MFMA accumulate.
// Table build: one thread per (table, n, 16-row block); 2 transcendental
// evals (base + step) then 15 EXACT geometric-recurrence complex mults.
// Same k-addressing for both operand tables -> any consistent k-permutation
// of the HW A/B fragment layout cancels; only the C/D layout (col=lane&15,
// row=4*(lane>>4)+reg, verified m89/m91) must be exact.
// Epilogue: stage 64x64 fp32 tile in (dead) operand LDS, stream out as
// 4KB-contiguous PLAIN stores — output (16.8 MB) is L2/L3-resident across
// graph replays; nontemporal would force a synchronous 2.7+ us HBM drain.
__global__ __launch_bounds__(256) void s4d_mfma_kernel(
    const float* __restrict__ log_A_real,  // (D,N)
    const float* __restrict__ A_imag,      // (D,N)
    const float* __restrict__ Bp,          // (D,N,2)
    const float* __restrict__ Cp,          // (D,N,2)
    const float* __restrict__ log_dt,      // (D,)
    float* __restrict__ K,                 // (D,L), L=4096
    int L) {
  const int d = blockIdx.x;
  const int tid = threadIdx.x;

  // 16 KB: two 8 KB f16 operand tables; reused as the 64x64 fp32 out-stage.
  __shared__ __align__(16) char s_tab[2][64 * 128];
  f16* s_U = (f16*)s_tab[0];
  f16* s_V = (f16*)s_tab[1];
  float* s_out = (float*)s_tab;

  // Phase 1+2 fused: task = (uh, n, rblk). uh=0 -> U table, uh=1 -> V.
  {
    const int uh = tid >> 7;
    const int n = tid & 31;
    const int rblk = (tid >> 5) & 3;  // rows 16*rblk .. 16*rblk+15
    const int idx = d * N_STATE + n;

    const float dt = softplus_hw(log_dt[d]);
    const float wr = -dt * softplus_hw(log_A_real[idx]);  // dt*A_real < 0
    const float wi = dt * A_imag[idx];                    // dt*A_imag >= 0
    const float wrl2e = wr * 1.4426950408889634f;   // for v_exp_f32
    const float wirev = wi * 0.15915494309189535f;  // revolutions

    // base = z^sf0 (V: sf0=16*rblk) or z^(64*a0) (U: sf0=1024*rblk);
    // step m = z (V) or M=z^64 (U).
    const float sf0 = uh ? (float)(16 * rblk) : (float)(1024 * rblk);
    const float sst = uh ? 1.0f : 64.0f;
    const float eb = __builtin_amdgcn_exp2f(wrl2e * sf0);
    const float phb = __builtin_amdgcn_fractf(wirev * sf0);
    float pr = eb * __builtin_amdgcn_cosf(phb);
    float pq = eb * __builtin_amdgcn_sinf(phb);
    const float em = __builtin_amdgcn_exp2f(wrl2e * sst);
    const float phm = __builtin_amdgcn_fractf(wirev * sst);
    float mr = em * __builtin_amdgcn_cosf(phm);
    float mi = em * __builtin_amdgcn_sinf(phm);

    if (uh == 0) {
      // p = G * base, G = Cc*Bc
      const float br = Bp[2 * idx], bi = Bp[2 * idx + 1];
      const float cr = Cp[2 * idx], ci = Cp[2 * idx + 1];
      const float gr = cr * br - ci * bi;
      const float gi = cr * bi + ci * br;
      const float tr = gr * pr - gi * pq;
      pq = gr * pq + gi * pr;
      pr = tr;
    } else {
      // conjugate state & step: stored pair becomes (Re z^b, -Im z^b)
      pq = -pq;
      mi = -mi;
    }

    char* tab = s_tab[uh];
    const int r0 = 16 * rblk;
#pragma unroll
    for (int j = 0; j < 16; ++j) {
      union { fp16x2 v; unsigned u; } pk;
      pk.v = __builtin_amdgcn_cvt_pkrtz(pr, pq);
      *(unsigned*)(tab + swz(r0 + j, 4 * n)) = pk.u;
      const float nr = pr * mr - pq * mi;  // exact geometric step
      pq = pr * mi + pq * mr;
      pr = nr;
    }
  }
  __syncthreads();

  // Phase 3: wave wid owns output rows b in [16*wid, 16*wid+16).
  const int wid = tid >> 6;
  const int lane = tid & 63;
  const int r = lane & 15;   // A row (b) / B col (a) / D col
  const int g = lane >> 4;   // k-group

  f16x8 afrag[2];
#pragma unroll
  for (int kt = 0; kt < 2; ++kt)
    afrag[kt] = *(const f16x8*)((const char*)s_V +
                                swz(16 * wid + r, kt * 64 + g * 16));

  f32x4 acc[4];
#pragma unroll
  for (int nt = 0; nt < 4; ++nt) acc[nt] = (f32x4){0.f, 0.f, 0.f, 0.f};

#pragma unroll
  for (int nt = 0; nt < 4; ++nt) {
#pragma unroll
    for (int kt = 0; kt < 2; ++kt) {
      const f16x8 bfrag = *(const f16x8*)((const char*)s_U +
                                          swz(16 * nt + r, kt * 64 + g * 16));
      acc[nt] = __builtin_amdgcn_mfma_f32_16x16x32_f16(afrag[kt], bfrag,
                                                       acc[nt], 0, 0, 0);
    }
  }

  // Phase 4: stage D tiles into LDS (operand tables dead after MFMA).
  // D row = b = 16*wid + 4*g + reg, col = a = 16*nt + r; word = 64a + b.
  __syncthreads();  // WAR: all waves done reading s_U/s_V
#pragma unroll
  for (int nt = 0; nt < 4; ++nt) {
    const unsigned a = (unsigned)(16 * nt + r);
    const unsigned w = oswz(64u * a + (unsigned)(16 * wid + 4 * g));
    *(f32x4*)(s_out + w) = acc[nt];
  }
  __syncthreads();

  // Phase 5: stream out; 4KB contiguous per instruction across the block.
  // Plain (cacheable) stores: output is L2/L3-resident across replays.
  float* outd = K + (size_t)d * L;
#pragma unroll
  for (int i = 0; i < 4; ++i) {
    const unsigned f = (unsigned)(256 * i + tid);  // float4 index
    const f32x4 v = *(const f32x4*)(s_out + oswz(4u * f));
    *(f32x4*)(outd + 4u * f) = v;
  }
}

extern "C" void kernel_launch(void* const* d_in, const int* in_sizes, int n_in,
                              void* d_out, int out_size, void* d_ws,
                              size_t ws_size, hipStream_t stream) {
  const float* log_A_real = (const float*)d_in[0];
  const float* A_imag = (const float*)d_in[1];
  const float* B = (const float*)d_in[2];
  const float* C = (const float*)d_in[3];
  const float* log_dt = (const float*)d_in[4];
  float* K = (float*)d_out;

  const int D = in_sizes[4];   // 1024
  const int L = out_size / D;  // 4096 (kernel assumes 64x64 factorization)

  dim3 grid(D), block(256);
  hipLaunchKernelGGL(s4d_mfma_kernel, grid, block, 0, stream, log_A_real,
                     A_imag, B, C, log_dt, K, L);
}

// Round 9
// 10.495 us; speedup vs baseline: 1.0815x; 1.0815x over previous
//
#include <hip/hip_runtime.h>
#include <math.h>

#define N_STATE 32

typedef _Float16 f16;
typedef __fp16 fp16x2 __attribute__((ext_vector_type(2)));
typedef f16 f16x8 __attribute__((ext_vector_type(8)));
typedef float f32x4 __attribute__((ext_vector_type(4)));

// Swizzled byte offset inside a [64 rows][64 f16] table (128 B rows).
// XOR of (row&7) into byte bits 4-6 spreads column-slice ds_read_b128s
// (fixed k, varying row) across banks; same function on write & read
// (rule #21). XOR touches bits 4-6 only -> 4B/8B/16B units stay intact.
__device__ __forceinline__ unsigned swz(int row, int byte_in_row) {
  return (unsigned)(((row << 7) + byte_in_row) ^ ((row & 7) << 4));
}

// Output-staging swizzle on fp32 word index (logical word 64*a + b).
__device__ __forceinline__ unsigned oswz(unsigned word) {
  return word ^ (((word >> 6) & 7u) << 2);
}

// softplus via HW transcendentals: ln(1+e^x) = ln2 * log2(1 + exp2(x*log2e)).
__device__ __forceinline__ float softplus_hw(float x) {
  const float t = __builtin_amdgcn_exp2f(x * 1.4426950408889634f);
  return 0.6931471805599453f * __builtin_amdgcn_logf(1.0f + t);
}

// One block (256 threads = 4 waves) per NDB d-rows, looped.
//   K[d, 64a+b] = sum_k V'[b,k] U'[k,a]   (V as MFMA-A, U as MFMA-B)
//   V'[b,2n] = Re(z_n^b),  V'[b,2n+1] = -Im(z_n^b)
//   U'[2n,a] = Re(G M^a),  U'[2n+1,a] =  Im(G M^a)
// z = exp(dt*A), M = z^64, G = Cc*Bc. f16 operands, fp32 MFMA accumulate.
// Looping NDB rows per block lets iteration i's nontemporal-store drain
// (~0.7 us/iter of HBM time) overlap iteration i+1's table build + MFMA —
// with one block-generation per grid the drain was fully exposed at the end.
// Same k-addressing for both operand tables -> any consistent k-permutation
// of the HW A/B fragment layout cancels; only the C/D layout (col=lane&15,
// row=4*(lane>>4)+reg, verified m89/m91) must be exact.
template <int NDB>
__global__ __launch_bounds__(256) void s4d_mfma_kernel(
    const float* __restrict__ log_A_real,  // (D,N)
    const float* __restrict__ A_imag,      // (D,N)
    const float* __restrict__ Bp,          // (D,N,2)
    const float* __restrict__ Cp,          // (D,N,2)
    const float* __restrict__ log_dt,      // (D,)
    float* __restrict__ K,                 // (D,L), L=4096
    int L) {
  const int d0 = blockIdx.x * NDB;
  const int tid = threadIdx.x;

  // 16 KB: two 8 KB f16 operand tables; reused as the 64x64 fp32 out-stage.
  __shared__ __align__(16) char s_tab[2][64 * 128];
  f16* s_U = (f16*)s_tab[0];
  f16* s_V = (f16*)s_tab[1];
  float* s_out = (float*)s_tab;

  // Loop-invariant thread decompositions.
  const int uh = tid >> 7;          // 0 -> U table, 1 -> V table
  const int n = tid & 31;
  const int rblk = (tid >> 5) & 3;  // rows 16*rblk .. 16*rblk+15
  const float sf0 = uh ? (float)(16 * rblk) : (float)(1024 * rblk);
  const float sst = uh ? 1.0f : 64.0f;
  const int wid = tid >> 6;
  const int lane = tid & 63;
  const int r = lane & 15;          // A row (b) / B col (a) / D col
  const int g = lane >> 4;          // k-group

  for (int it = 0; it < NDB; ++it) {
    const int d = d0 + it;

    // Phase 1+2: build tables. task = (uh, n, rblk); 2 transcendental evals
    // (base + step) then 15 exact geometric-recurrence complex mults.
    {
      const int idx = d * N_STATE + n;
      const float dt = softplus_hw(log_dt[d]);
      const float wr = -dt * softplus_hw(log_A_real[idx]);  // dt*A_real < 0
      const float wi = dt * A_imag[idx];                    // dt*A_imag >= 0
      const float wrl2e = wr * 1.4426950408889634f;   // for v_exp_f32
      const float wirev = wi * 0.15915494309189535f;  // revolutions

      const float eb = __builtin_amdgcn_exp2f(wrl2e * sf0);
      const float phb = __builtin_amdgcn_fractf(wirev * sf0);
      float pr = eb * __builtin_amdgcn_cosf(phb);
      float pq = eb * __builtin_amdgcn_sinf(phb);
      const float em = __builtin_amdgcn_exp2f(wrl2e * sst);
      const float phm = __builtin_amdgcn_fractf(wirev * sst);
      float mr = em * __builtin_amdgcn_cosf(phm);
      float mi = em * __builtin_amdgcn_sinf(phm);

      if (uh == 0) {
        const float br = Bp[2 * idx], bi = Bp[2 * idx + 1];
        const float cr = Cp[2 * idx], ci = Cp[2 * idx + 1];
        const float gr = cr * br - ci * bi;  // G = Cc*Bc
        const float gi = cr * bi + ci * br;
        const float tr = gr * pr - gi * pq;
        pq = gr * pq + gi * pr;
        pr = tr;
      } else {
        pq = -pq;  // conjugate: stored pair becomes (Re z^b, -Im z^b)
        mi = -mi;
      }

      char* tab = s_tab[uh];
      const int r0 = 16 * rblk;
#pragma unroll
      for (int j = 0; j < 16; ++j) {
        union { fp16x2 v; unsigned u; } pk;
        pk.v = __builtin_amdgcn_cvt_pkrtz(pr, pq);
        *(unsigned*)(tab + swz(r0 + j, 4 * n)) = pk.u;
        const float nr = pr * mr - pq * mi;  // exact geometric step
        pq = pr * mi + pq * mr;
        pr = nr;
      }
    }
    __syncthreads();

    // Phase 3: wave wid owns output rows b in [16*wid, 16*wid+16).
    f16x8 afrag[2];
#pragma unroll
    for (int kt = 0; kt < 2; ++kt)
      afrag[kt] = *(const f16x8*)((const char*)s_V +
                                  swz(16 * wid + r, kt * 64 + g * 16));

    f32x4 acc[4];
#pragma unroll
    for (int nt = 0; nt < 4; ++nt) acc[nt] = (f32x4){0.f, 0.f, 0.f, 0.f};

#pragma unroll
    for (int nt = 0; nt < 4; ++nt) {
#pragma unroll
      for (int kt = 0; kt < 2; ++kt) {
        const f16x8 bfrag = *(const f16x8*)(
            (const char*)s_U + swz(16 * nt + r, kt * 64 + g * 16));
        acc[nt] = __builtin_amdgcn_mfma_f32_16x16x32_f16(afrag[kt], bfrag,
                                                         acc[nt], 0, 0, 0);
      }
    }

    // Phase 4: stage D tiles into LDS (operand tables dead after MFMA).
    // D row = b = 16*wid + 4*g + reg, col = a = 16*nt + r; word = 64a + b.
    __syncthreads();  // WAR: all waves done reading s_U/s_V
#pragma unroll
    for (int nt = 0; nt < 4; ++nt) {
      const unsigned a = (unsigned)(16 * nt + r);
      const unsigned w = oswz(64u * a + (unsigned)(16 * wid + 4 * g));
      *(f32x4*)(s_out + w) = acc[nt];
    }
    __syncthreads();

    // Phase 5: stream out; 4KB contiguous per instruction across the block
    // -> full-line nontemporal HBM writes (drain overlaps next iteration).
    float* outd = K + (size_t)d * L;
#pragma unroll
    for (int i = 0; i < 4; ++i) {
      const unsigned f = (unsigned)(256 * i + tid);  // float4 index
      const f32x4 v = *(const f32x4*)(s_out + oswz(4u * f));
      __builtin_nontemporal_store(v, (f32x4*)(outd + 4u * f));
    }
    __syncthreads();  // WAR: phase-5 LDS reads done before next table build
  }
}

extern "C" void kernel_launch(void* const* d_in, const int* in_sizes, int n_in,
                              void* d_out, int out_size, void* d_ws,
                              size_t ws_size, hipStream_t stream) {
  const float* log_A_real = (const float*)d_in[0];
  const float* A_imag = (const float*)d_in[1];
  const float* B = (const float*)d_in[2];
  const float* C = (const float*)d_in[3];
  const float* log_dt = (const float*)d_in[4];
  float* K = (float*)d_out;

  const int D = in_sizes[4];   // 1024
  const int L = out_size / D;  // 4096 (kernel assumes 64x64 factorization)

  constexpr int NDB = 2;       // d-rows per block
  dim3 grid(D / NDB), block(256);
  hipLaunchKernelGGL(s4d_mfma_kernel<NDB>, grid, block, 0, stream, log_A_real,
                     A_imag, B, C, log_dt, K, L);
}